// Round 1
// baseline (2350.122 us; speedup 1.0000x reference)
//
#include <hip/hip_runtime.h>

#define BB 4
#define NN 16384
#define CC 384
#define DD 192
#define MM 1024

__device__ __forceinline__ float4 ld4(const float* p) { return *reinterpret_cast<const float4*>(p); }

// ---------------- K1: patchify conv -> x2c[b][o][m], m = ph*32+pw ----------------
// grid BB*64, 256 thr. Block: 16 patches x 192 outputs, K=3072 in chunks of 64 (4 in-ch x 16 px).
__global__ __launch_bounds__(256) void k_conv(const float* __restrict__ x,
                                              const float* __restrict__ cw,
                                              const float* __restrict__ cb,
                                              float* __restrict__ x2c)
{
    __shared__ float A[64][20];    // [k_local][patch]
    __shared__ float W[64][198];   // [k_local][o]
    const int blk = blockIdx.x;
    const int b = blk >> 6, mt = blk & 63;
    const int ph = mt >> 1, pw0 = (mt & 1) * 16;
    const int t = threadIdx.x;
    const int og = t & 31, pg = t >> 5;   // o0 = og*6, p0 = pg*2
    float acc[2][6] = {};
    for (int i0 = 0; i0 < DD; i0 += 4) {
        __syncthreads();
        {   // A: 4 pixel-rows x 64 cols, one float4 (4 channels) per thread
            int kh = t >> 6, wl = t & 63;
            int n = (ph * 4 + kh) * 128 + pw0 * 4 + wl;
            float4 v = ld4(&x[(size_t)(b * NN + n) * CC + DD + i0]);
            int pl = wl >> 2, kw = wl & 3, px = kh * 4 + kw;
            A[px][pl] = v.x; A[16 + px][pl] = v.y; A[32 + px][pl] = v.z; A[48 + px][pl] = v.w;
        }
        #pragma unroll
        for (int j = 0; j < 3; ++j) {   // W: 192 o x 64 k
            int task = t + 256 * j;
            int o = task >> 2, q = task & 3;
            const float* src = &cw[(size_t)o * 3072 + i0 * 16 + q * 16];
            #pragma unroll
            for (int e4 = 0; e4 < 4; ++e4) {
                float4 v = ld4(src + e4 * 4);
                W[q * 16 + e4 * 4 + 0][o] = v.x;
                W[q * 16 + e4 * 4 + 1][o] = v.y;
                W[q * 16 + e4 * 4 + 2][o] = v.z;
                W[q * 16 + e4 * 4 + 3][o] = v.w;
            }
        }
        __syncthreads();
        #pragma unroll 4
        for (int kk = 0; kk < 64; ++kk) {
            float2 av = *reinterpret_cast<const float2*>(&A[kk][pg * 2]);
            #pragma unroll
            for (int j = 0; j < 6; ++j) {
                float w = W[kk][og * 6 + j];
                acc[0][j] += av.x * w;
                acc[1][j] += av.y * w;
            }
        }
    }
    const int m = ph * 32 + pw0 + pg * 2;
    #pragma unroll
    for (int j = 0; j < 6; ++j) {
        int o = og * 6 + j;
        float bias = cb[o];
        size_t off = (size_t)(b * DD + o) * MM + m;
        x2c[off]     = acc[0][j] + bias;
        x2c[off + 1] = acc[1][j] + bias;
    }
}

// ---------------- K2: split-K partials of S[d][e] = sum_n x1[n,d]*x2[n,e] ----------------
// grid BB*6*16 (b, e-tile of 32, k-split of 1024), 256 thr; thread: 6 d x 4 e accs.
__global__ __launch_bounds__(256) void k_spart(const float* __restrict__ x, float* __restrict__ Sp)
{
    __shared__ float X1[32][196];
    __shared__ float X2[32][36];
    const int blk = blockIdx.x;
    const int ks = blk & 15;
    const int et = (blk >> 4) % 6;
    const int b  = blk / 96;
    const int t = threadIdx.x;
    const int eg = t & 7, dg = t >> 3;
    float acc[6][4] = {};
    for (int ch = 0; ch < 32; ++ch) {
        const int kb = ks * 1024 + ch * 32;
        __syncthreads();
        #pragma unroll
        for (int j = 0; j < 6; ++j) {
            int idx = t + 256 * j;
            int row = idx / 48, c4 = idx % 48;
            *reinterpret_cast<float4*>(&X1[row][c4 * 4]) =
                ld4(&x[(size_t)(b * NN + kb + row) * CC + c4 * 4]);
        }
        {
            int row = t >> 3, c4 = t & 7;
            *reinterpret_cast<float4*>(&X2[row][c4 * 4]) =
                ld4(&x[(size_t)(b * NN + kb + row) * CC + DD + et * 32 + c4 * 4]);
        }
        __syncthreads();
        #pragma unroll 4
        for (int kk = 0; kk < 32; ++kk) {
            float4 bv = *reinterpret_cast<const float4*>(&X2[kk][eg * 4]);
            #pragma unroll
            for (int i = 0; i < 6; ++i) {
                float a = X1[kk][dg * 6 + i];
                acc[i][0] += a * bv.x; acc[i][1] += a * bv.y;
                acc[i][2] += a * bv.z; acc[i][3] += a * bv.w;
            }
        }
    }
    #pragma unroll
    for (int i = 0; i < 6; ++i) {
        int d = dg * 6 + i;
        size_t off = ((size_t)(ks * BB + b) * DD + d) * DD + et * 32 + eg * 4;
        *reinterpret_cast<float4*>(&Sp[off]) = make_float4(acc[i][0], acc[i][1], acc[i][2], acc[i][3]);
    }
}

// ---------------- K3a: reduce 16 partials -> S ----------------
__global__ __launch_bounds__(256) void k_sreduce(const float* __restrict__ Sp, float* __restrict__ S)
{
    int idx = blockIdx.x * 256 + threadIdx.x;   // < BB*36864
    int b = idx / 36864, de = idx % 36864;
    float s = 0.f;
    #pragma unroll
    for (int p = 0; p < 16; ++p) s += Sp[(size_t)(p * BB + b) * 36864 + de];
    S[(size_t)b * 36864 + de] = s;
}

// ---------------- K3b: softmax over d (axis -2), in place ----------------
__global__ __launch_bounds__(192) void k_softmax(float* __restrict__ S)
{
    const int b = blockIdx.x, e = threadIdx.x;
    float* Sb = S + (size_t)b * 36864;
    float m = -3.4e38f;
    for (int d = 0; d < DD; ++d) m = fmaxf(m, Sb[d * DD + e]);
    float sum = 0.f;
    for (int d = 0; d < DD; ++d) {
        float v = __expf(Sb[d * DD + e] - m);
        Sb[d * DD + e] = v;
        sum += v;
    }
    float inv = 1.f / sum;
    for (int d = 0; d < DD; ++d) Sb[d * DD + e] *= inv;
}

// ---------------- K4: fused gate/sp + ch + LN + proj + transposed store ----------------
// grid BB*512 (32 rows each), 256 thr.
__global__ __launch_bounds__(256) void k_fused(const float* __restrict__ x,
                                               const float* __restrict__ x2c,
                                               const float* __restrict__ att,
                                               const float* __restrict__ lnw,
                                               const float* __restrict__ lnb,
                                               const float* __restrict__ pw,
                                               const float* __restrict__ pb,
                                               float* __restrict__ out)
{
    __shared__ float X1T[DD][34];   // x1 transposed [d][row]
    __shared__ float X2T[DD][34];   // x2 transposed [d][row]
    __shared__ float SC[13056];     // union: xc[192][68] | att_t[192][68] | cat[32][388]
    __shared__ float GT[32][68];    // gate[32 rows][64 m] (pitch 68) | LN reduction scratch

    const int t = threadIdx.x;
    const int blk = blockIdx.x;
    const int b = blk >> 9;
    const int n0 = (blk & 511) << 5;

    // P0: load x rows transposed into X1T/X2T
    #pragma unroll
    for (int j = 0; j < 12; ++j) {
        int idx = t + 256 * j;
        int row = idx / 96, c4 = idx % 96;
        float4 v = ld4(&x[(size_t)(b * NN + n0 + row) * CC + c4 * 4]);
        if (c4 < 48) {
            int d0 = c4 * 4;
            X1T[d0 + 0][row] = v.x; X1T[d0 + 1][row] = v.y;
            X1T[d0 + 2][row] = v.z; X1T[d0 + 3][row] = v.w;
        } else {
            int d0 = (c4 - 48) * 4;
            X2T[d0 + 0][row] = v.x; X2T[d0 + 1][row] = v.y;
            X2T[d0 + 2][row] = v.z; X2T[d0 + 3][row] = v.w;
        }
    }
    __syncthreads();

    const int r2 = t >> 4;   // logits/ch layout: rows r2*2+rr
    const int tg = t & 15;   // m/e quad: tg*4
    const int dg = t & 31;   // sp layout: d = dg + 32*i
    const int rg = t >> 5;   // sp layout: rows rg*4+rr

    // P1: gate logits -> sigmoid -> sp accumulation over 16 m-chunks of 64
    float spa[4][6] = {};
    for (int mc = 0; mc < 16; ++mc) {
        const int m0 = mc << 6;
        #pragma unroll
        for (int j = 0; j < 12; ++j) {
            int idx = t + 256 * j;
            int d = idx >> 4, c4 = idx & 15;
            *reinterpret_cast<float4*>(&SC[d * 68 + c4 * 4]) =
                ld4(&x2c[(size_t)(b * DD + d) * MM + m0 + c4 * 4]);
        }
        __syncthreads();
        float la[2][4] = {};
        #pragma unroll 4
        for (int d = 0; d < DD; ++d) {
            float2 a2 = *reinterpret_cast<const float2*>(&X1T[d][r2 * 2]);
            float4 xv = *reinterpret_cast<const float4*>(&SC[d * 68 + tg * 4]);
            la[0][0] += a2.x * xv.x; la[0][1] += a2.x * xv.y;
            la[0][2] += a2.x * xv.z; la[0][3] += a2.x * xv.w;
            la[1][0] += a2.y * xv.x; la[1][1] += a2.y * xv.y;
            la[1][2] += a2.y * xv.z; la[1][3] += a2.y * xv.w;
        }
        #pragma unroll
        for (int rr = 0; rr < 2; ++rr) {
            float4 g;
            g.x = 1.f / (1.f + __expf(-la[rr][0]));
            g.y = 1.f / (1.f + __expf(-la[rr][1]));
            g.z = 1.f / (1.f + __expf(-la[rr][2]));
            g.w = 1.f / (1.f + __expf(-la[rr][3]));
            *reinterpret_cast<float4*>(&GT[r2 * 2 + rr][tg * 4]) = g;
        }
        __syncthreads();
        #pragma unroll 2
        for (int m4 = 0; m4 < 16; ++m4) {
            float4 gv[4];
            #pragma unroll
            for (int rr = 0; rr < 4; ++rr)
                gv[rr] = *reinterpret_cast<const float4*>(&GT[rg * 4 + rr][m4 * 4]);
            #pragma unroll
            for (int i = 0; i < 6; ++i) {
                float4 xv = *reinterpret_cast<const float4*>(&SC[(dg + 32 * i) * 68 + m4 * 4]);
                #pragma unroll
                for (int rr = 0; rr < 4; ++rr)
                    spa[rr][i] += gv[rr].x * xv.x + gv[rr].y * xv.y + gv[rr].z * xv.z + gv[rr].w * xv.w;
            }
        }
        __syncthreads();
    }

    // P2: ch = x2 @ att (att via LDS tiles of 64 e)
    float chv[2][12] = {};
    for (int et = 0; et < 3; ++et) {
        #pragma unroll
        for (int j = 0; j < 12; ++j) {
            int idx = t + 256 * j;
            int d = idx >> 4, c4 = idx & 15;
            *reinterpret_cast<float4*>(&SC[d * 68 + c4 * 4]) =
                ld4(&att[(size_t)b * 36864 + d * DD + et * 64 + c4 * 4]);
        }
        __syncthreads();
        #pragma unroll 4
        for (int d = 0; d < DD; ++d) {
            float2 a2 = *reinterpret_cast<const float2*>(&X2T[d][r2 * 2]);
            float4 av = *reinterpret_cast<const float4*>(&SC[d * 68 + tg * 4]);
            chv[0][et * 4 + 0] += a2.x * av.x; chv[0][et * 4 + 1] += a2.x * av.y;
            chv[0][et * 4 + 2] += a2.x * av.z; chv[0][et * 4 + 3] += a2.x * av.w;
            chv[1][et * 4 + 0] += a2.y * av.x; chv[1][et * 4 + 1] += a2.y * av.y;
            chv[1][et * 4 + 2] += a2.y * av.z; chv[1][et * 4 + 3] += a2.y * av.w;
        }
        __syncthreads();
    }

    // write cat = [sp | ch] into SC as cat[32][388]
    #pragma unroll
    for (int rr = 0; rr < 4; ++rr)
        #pragma unroll
        for (int i = 0; i < 6; ++i)
            SC[(rg * 4 + rr) * 388 + dg + 32 * i] = spa[rr][i];
    #pragma unroll
    for (int rr = 0; rr < 2; ++rr)
        #pragma unroll
        for (int et = 0; et < 3; ++et) {
            float4 v = make_float4(chv[rr][et * 4 + 0], chv[rr][et * 4 + 1],
                                   chv[rr][et * 4 + 2], chv[rr][et * 4 + 3]);
            *reinterpret_cast<float4*>(&SC[(r2 * 2 + rr) * 388 + DD + et * 64 + tg * 4]) = v;
        }
    __syncthreads();

    // P3: LayerNorm rows of cat
    const int r3 = t & 31;
    const int tg3 = t >> 5;
    {
        float s = 0.f, ss = 0.f;
        #pragma unroll
        for (int q4 = 0; q4 < 12; ++q4) {
            float4 v = *reinterpret_cast<const float4*>(&SC[r3 * 388 + tg3 * 48 + q4 * 4]);
            s  += v.x + v.y + v.z + v.w;
            ss += v.x * v.x + v.y * v.y + v.z * v.z + v.w * v.w;
        }
        GT[r3][tg3] = s;
        GT[r3][8 + tg3] = ss;
    }
    __syncthreads();
    if (t < 32) {
        float a = 0.f, c = 0.f;
        #pragma unroll
        for (int j = 0; j < 8; ++j) { a += GT[t][j]; c += GT[t][8 + j]; }
        float mu = a * (1.f / 384.f);
        float var = c * (1.f / 384.f) - mu * mu;
        GT[t][16] = mu;
        GT[t][17] = rsqrtf(var + 1e-5f);
    }
    __syncthreads();
    {
        float mu = GT[r3][16], rs = GT[r3][17];
        #pragma unroll
        for (int q4 = 0; q4 < 12; ++q4) {
            int c = tg3 * 48 + q4 * 4;
            float4 v = *reinterpret_cast<float4*>(&SC[r3 * 388 + c]);
            float4 w = ld4(&lnw[c]);
            float4 bb = ld4(&lnb[c]);
            v.x = (v.x - mu) * rs * w.x + bb.x;
            v.y = (v.y - mu) * rs * w.y + bb.y;
            v.z = (v.z - mu) * rs * w.z + bb.z;
            v.w = (v.w - mu) * rs * w.w + bb.w;
            *reinterpret_cast<float4*>(&SC[r3 * 388 + c]) = v;
        }
    }
    __syncthreads();

    // P4: proj (384x384) with proj_w chunks staged transposed into X1T region
    float* PW = &X1T[0][0];          // 16*384 = 6144 floats <= 6528
    const int og = t & 31, rg4 = t >> 5;
    const int o0 = og * 12;
    float pa[4][12] = {};
    for (int c0 = 0; c0 < CC; c0 += 16) {
        #pragma unroll
        for (int j = 0; j < 6; ++j) {
            int idx = t + 256 * j;
            int o = idx >> 2, q = idx & 3;
            float4 v = ld4(&pw[(size_t)o * CC + c0 + q * 4]);
            PW[(q * 4 + 0) * 384 + o] = v.x;
            PW[(q * 4 + 1) * 384 + o] = v.y;
            PW[(q * 4 + 2) * 384 + o] = v.z;
            PW[(q * 4 + 3) * 384 + o] = v.w;
        }
        __syncthreads();
        #pragma unroll
        for (int cs = 0; cs < 4; ++cs) {
            float lvf[4][4];
            #pragma unroll
            for (int rr = 0; rr < 4; ++rr) {
                float4 v = *reinterpret_cast<const float4*>(&SC[(rg4 * 4 + rr) * 388 + c0 + cs * 4]);
                lvf[rr][0] = v.x; lvf[rr][1] = v.y; lvf[rr][2] = v.z; lvf[rr][3] = v.w;
            }
            #pragma unroll
            for (int cc = 0; cc < 4; ++cc) {
                const float* wp = &PW[(cs * 4 + cc) * 384 + o0];
                float4 w0 = *reinterpret_cast<const float4*>(wp);
                float4 w1 = *reinterpret_cast<const float4*>(wp + 4);
                float4 w2 = *reinterpret_cast<const float4*>(wp + 8);
                #pragma unroll
                for (int rr = 0; rr < 4; ++rr) {
                    float l = lvf[rr][cc];
                    pa[rr][0]  += l * w0.x; pa[rr][1]  += l * w0.y; pa[rr][2]  += l * w0.z; pa[rr][3]  += l * w0.w;
                    pa[rr][4]  += l * w1.x; pa[rr][5]  += l * w1.y; pa[rr][6]  += l * w1.z; pa[rr][7]  += l * w1.w;
                    pa[rr][8]  += l * w2.x; pa[rr][9]  += l * w2.y; pa[rr][10] += l * w2.z; pa[rr][11] += l * w2.w;
                }
            }
        }
        __syncthreads();
    }
    #pragma unroll
    for (int j = 0; j < 12; ++j) {
        int o = o0 + j;
        float bias = pb[o];
        float4 ov = make_float4(pa[0][j] + bias, pa[1][j] + bias, pa[2][j] + bias, pa[3][j] + bias);
        *reinterpret_cast<float4*>(&out[(size_t)(b * CC + o) * NN + n0 + rg4 * 4]) = ov;
    }
}

extern "C" void kernel_launch(void* const* d_in, const int* in_sizes, int n_in,
                              void* d_out, int out_size, void* d_ws, size_t ws_size,
                              hipStream_t stream)
{
    (void)in_sizes; (void)n_in; (void)out_size; (void)ws_size;
    const float* x   = (const float*)d_in[0];
    const float* cw  = (const float*)d_in[1];
    const float* cb  = (const float*)d_in[2];
    const float* lnw = (const float*)d_in[3];
    const float* lnb = (const float*)d_in[4];
    const float* pwm = (const float*)d_in[5];
    const float* pbv = (const float*)d_in[6];
    float* out = (float*)d_out;
    float* ws  = (float*)d_ws;

    float* x2c  = ws;                        // 786432 floats
    float* Sp   = ws + 786432;               // 16*4*36864 = 2359296 floats
    float* Satt = ws + 786432 + 2359296;     // 147456 floats

    hipLaunchKernelGGL(k_conv,    dim3(BB * 64),  dim3(256), 0, stream, x, cw, cb, x2c);
    hipLaunchKernelGGL(k_spart,   dim3(BB * 96),  dim3(256), 0, stream, x, Sp);
    hipLaunchKernelGGL(k_sreduce, dim3(576),      dim3(256), 0, stream, Sp, Satt);
    hipLaunchKernelGGL(k_softmax, dim3(BB),       dim3(192), 0, stream, Satt);
    hipLaunchKernelGGL(k_fused,   dim3(BB * 512), dim3(256), 0, stream, x, x2c, Satt, lnw, lnb, pwm, pbv, out);
}

// Round 2
// 642.436 us; speedup vs baseline: 3.6581x; 3.6581x over previous
//
#include <hip/hip_runtime.h>

#define BB 4
#define NN 16384
#define CC 384
#define DD 192
#define MM 1024

typedef __attribute__((ext_vector_type(8))) short short8;
typedef __attribute__((ext_vector_type(4))) float f32x4;

__device__ __forceinline__ float4 ld4(const float* p) { return *reinterpret_cast<const float4*>(p); }

__device__ __forceinline__ unsigned short bf16r(float f) {
    unsigned int u = __float_as_uint(f);
    return (unsigned short)((u + 0x7FFFu + ((u >> 16) & 1u)) >> 16);
}
__device__ __forceinline__ unsigned int pk2(float a, float b) {
    return (unsigned int)bf16r(a) | ((unsigned int)bf16r(b) << 16);
}
__device__ __forceinline__ short8 as_s8(uint4 v) {
    union { uint4 u; short8 s; } x; x.u = v; return x.s;
}
__device__ __forceinline__ f32x4 mfma16(short8 a, short8 b, f32x4 c) {
    return __builtin_amdgcn_mfma_f32_16x16x32_bf16(a, b, c, 0, 0, 0);
}

// ---------------- K0: proj_w fp32 -> bf16 ----------------
__global__ __launch_bounds__(256) void k_prep(const float* __restrict__ pw, unsigned short* __restrict__ pwb)
{
    int i = blockIdx.x * 256 + threadIdx.x;   // 36864 groups of 4
    float4 v = ld4(&pw[i * 4]);
    uint2 o; o.x = pk2(v.x, v.y); o.y = pk2(v.z, v.w);
    reinterpret_cast<uint2*>(pwb)[i] = o;
}

// ---------------- K1: patchify conv -> x2cT[b][m][d] and x2cM[b][d][m] (bf16) ----------------
__global__ __launch_bounds__(256) void k_conv(const float* __restrict__ x,
                                              const float* __restrict__ cw,
                                              const float* __restrict__ cb,
                                              unsigned short* __restrict__ x2cT,
                                              unsigned short* __restrict__ x2cM)
{
    __shared__ float A[64][20];
    __shared__ float W[64][198];
    const int blk = blockIdx.x;
    const int b = blk >> 6, mt = blk & 63;
    const int ph = mt >> 1, pw0 = (mt & 1) * 16;
    const int t = threadIdx.x;
    const int og = t & 31, pg = t >> 5;
    float acc[2][6] = {};
    for (int i0 = 0; i0 < DD; i0 += 4) {
        __syncthreads();
        {
            int kh = t >> 6, wl = t & 63;
            int n = (ph * 4 + kh) * 128 + pw0 * 4 + wl;
            float4 v = ld4(&x[(size_t)(b * NN + n) * CC + DD + i0]);
            int pl = wl >> 2, kw = wl & 3, px = kh * 4 + kw;
            A[px][pl] = v.x; A[16 + px][pl] = v.y; A[32 + px][pl] = v.z; A[48 + px][pl] = v.w;
        }
        #pragma unroll
        for (int j = 0; j < 3; ++j) {
            int task = t + 256 * j;
            int o = task >> 2, q = task & 3;
            const float* src = &cw[(size_t)o * 3072 + i0 * 16 + q * 16];
            #pragma unroll
            for (int e4 = 0; e4 < 4; ++e4) {
                float4 v = ld4(src + e4 * 4);
                W[q * 16 + e4 * 4 + 0][o] = v.x;
                W[q * 16 + e4 * 4 + 1][o] = v.y;
                W[q * 16 + e4 * 4 + 2][o] = v.z;
                W[q * 16 + e4 * 4 + 3][o] = v.w;
            }
        }
        __syncthreads();
        #pragma unroll 4
        for (int kk = 0; kk < 64; ++kk) {
            float2 av = *reinterpret_cast<const float2*>(&A[kk][pg * 2]);
            #pragma unroll
            for (int j = 0; j < 6; ++j) {
                float w = W[kk][og * 6 + j];
                acc[0][j] += av.x * w;
                acc[1][j] += av.y * w;
            }
        }
    }
    const int m = ph * 32 + pw0 + pg * 2;
    const size_t bo = (size_t)b * 196608;
    #pragma unroll
    for (int j = 0; j < 6; ++j) {
        int o = og * 6 + j;
        float bias = cb[o];
        unsigned short b0 = bf16r(acc[0][j] + bias);
        unsigned short b1 = bf16r(acc[1][j] + bias);
        *reinterpret_cast<ushort2*>(x2cM + bo + (size_t)o * MM + m) = make_ushort2(b0, b1);
        x2cT[bo + (size_t)m * 192 + o] = b0;
        x2cT[bo + (size_t)(m + 1) * 192 + o] = b1;
    }
}

// ---------------- K2: split-K partials of S[d][e] (fp32, precision-critical) ----------------
__global__ __launch_bounds__(256) void k_spart(const float* __restrict__ x, float* __restrict__ Sp)
{
    __shared__ float X1[32][196];
    __shared__ float X2[32][36];
    const int blk = blockIdx.x;
    const int ks = blk & 7;
    const int et = (blk >> 3) % 6;
    const int b  = blk / 48;
    const int t = threadIdx.x;
    const int eg = t & 7, dg = t >> 3;
    float acc[6][4] = {};
    for (int ch = 0; ch < 64; ++ch) {
        const int kb = ks * 2048 + ch * 32;
        __syncthreads();
        #pragma unroll
        for (int j = 0; j < 6; ++j) {
            int idx = t + 256 * j;
            int row = idx / 48, c4 = idx % 48;
            *reinterpret_cast<float4*>(&X1[row][c4 * 4]) =
                ld4(&x[(size_t)(b * NN + kb + row) * CC + c4 * 4]);
        }
        {
            int row = t >> 3, c4 = t & 7;
            *reinterpret_cast<float4*>(&X2[row][c4 * 4]) =
                ld4(&x[(size_t)(b * NN + kb + row) * CC + DD + et * 32 + c4 * 4]);
        }
        __syncthreads();
        #pragma unroll 4
        for (int kk = 0; kk < 32; ++kk) {
            float4 bv = *reinterpret_cast<const float4*>(&X2[kk][eg * 4]);
            #pragma unroll
            for (int i = 0; i < 6; ++i) {
                float a = X1[kk][dg * 6 + i];
                acc[i][0] += a * bv.x; acc[i][1] += a * bv.y;
                acc[i][2] += a * bv.z; acc[i][3] += a * bv.w;
            }
        }
    }
    #pragma unroll
    for (int i = 0; i < 6; ++i) {
        int d = dg * 6 + i;
        size_t off = ((size_t)(ks * BB + b) * DD + d) * DD + et * 32 + eg * 4;
        *reinterpret_cast<float4*>(&Sp[off]) = make_float4(acc[i][0], acc[i][1], acc[i][2], acc[i][3]);
    }
}

// ---------------- K3a: reduce 8 partials -> S ----------------
__global__ __launch_bounds__(256) void k_sreduce(const float* __restrict__ Sp, float* __restrict__ S)
{
    int idx = blockIdx.x * 256 + threadIdx.x;
    int b = idx / 36864, de = idx % 36864;
    float s = 0.f;
    #pragma unroll
    for (int p = 0; p < 8; ++p) s += Sp[(size_t)(p * BB + b) * 36864 + de];
    S[(size_t)b * 36864 + de] = s;
}

// ---------------- K3b: softmax over d (fp32) -> attT[b][e][d] bf16 ----------------
__global__ __launch_bounds__(64) void k_softmax(const float* __restrict__ S, unsigned short* __restrict__ attT)
{
    const int bid = blockIdx.x;
    const int b = bid / 192, e = bid % 192;
    const int l = threadIdx.x;
    const float* Sb = S + (size_t)b * 36864 + e;
    float v0 = Sb[(size_t)(l * 3 + 0) * 192];
    float v1 = Sb[(size_t)(l * 3 + 1) * 192];
    float v2 = Sb[(size_t)(l * 3 + 2) * 192];
    float m = fmaxf(fmaxf(v0, v1), v2);
    #pragma unroll
    for (int s = 1; s < 64; s <<= 1) m = fmaxf(m, __shfl_xor(m, s, 64));
    v0 = __expf(v0 - m); v1 = __expf(v1 - m); v2 = __expf(v2 - m);
    float sum = v0 + v1 + v2;
    #pragma unroll
    for (int s = 1; s < 64; s <<= 1) sum += __shfl_xor(sum, s, 64);
    float inv = __fdividef(1.f, sum);
    unsigned short* dst = attT + (size_t)b * 36864 + (size_t)e * 192 + l * 3;
    dst[0] = bf16r(v0 * inv); dst[1] = bf16r(v1 * inv); dst[2] = bf16r(v2 * inv);
}

// ---------------- K4: fused MFMA kernel ----------------
// 512 thr (8 waves = 4 row-groups x 2 col-halves), 128 rows/block, grid B*128.
#define OFF_CT 49152
#define OFF_CM 73728
#define OFF_GT 98304
#define OFF_CB 0
#define OFF_CA 51200
#define OFF_PW 102400

__global__ __launch_bounds__(512, 2) void k_fused(
    const float* __restrict__ x, const unsigned short* __restrict__ x2cT,
    const unsigned short* __restrict__ x2cM, const unsigned short* __restrict__ attT,
    const float* __restrict__ lnw, const float* __restrict__ lnb,
    const unsigned short* __restrict__ pwb, const float* __restrict__ pb,
    float* __restrict__ out)
{
    __shared__ alignas(16) char LB[126976];
    const int t = threadIdx.x;
    const int l = t & 63, w = t >> 6;
    const int rg = w >> 1, cs = w & 1;
    const int b = blockIdx.x >> 7;
    const int n0 = (blockIdx.x & 127) << 7;
    const int l15 = l & 15, l4 = l >> 4, l7 = l & 7;
    const size_t xrow0 = (size_t)(b * NN + n0) * CC;
    const size_t cbo = (size_t)b * 196608;

    // ---- stage x1 (bf16, XOR-swizzled) ----
    #pragma unroll
    for (int j = 0; j < 6; ++j) {
        int u = j * 512 + t;
        int row = u / 24, d8 = (u % 24) * 8;
        const float* src = &x[xrow0 + (size_t)row * CC + d8];
        float4 v0 = ld4(src), v1 = ld4(src + 4);
        uint4 pv = make_uint4(pk2(v0.x, v0.y), pk2(v0.z, v0.w), pk2(v1.x, v1.y), pk2(v1.z, v1.w));
        *reinterpret_cast<uint4*>(LB + (((row * 192 + d8) * 2) ^ ((row & 7) << 4))) = pv;
    }
    // prologue: prefetch chunk 0 of x2cT/x2cM
    uint4 stT[3], stM[3];
    {
        #pragma unroll
        for (int j = 0; j < 3; ++j) {
            int u = j * 512 + t;
            int m = u / 24, d8 = (u % 24) * 8;
            stT[j] = *reinterpret_cast<const uint4*>(x2cT + cbo + (size_t)m * 192 + d8);
            int d = u >> 3, m8 = (u & 7) * 8;
            stM[j] = *reinterpret_cast<const uint4*>(x2cM + cbo + (size_t)d * MM + m8);
        }
    }
    __syncthreads();

    // x1 A-fragments (resident across all chunks)
    short8 ax1[2][6];
    #pragma unroll
    for (int rt = 0; rt < 2; ++rt) {
        int row = rg * 32 + rt * 16 + l15;
        #pragma unroll
        for (int k = 0; k < 6; ++k)
            ax1[rt][k] = *reinterpret_cast<const short8*>(
                LB + (((row * 192 + k * 32 + l4 * 8) * 2) ^ ((row & 7) << 4)));
    }

    f32x4 spa[2][6];
    #pragma unroll
    for (int rt = 0; rt < 2; ++rt)
        #pragma unroll
        for (int nt = 0; nt < 6; ++nt) spa[rt][nt] = (f32x4){0.f, 0.f, 0.f, 0.f};

    // ---- Phase A: 16 m-chunks of 64: gate = sigmoid(x1 @ x2c), sp += gate @ x2c^T ----
    for (int mc = 0; mc < 16; ++mc) {
        __syncthreads();
        #pragma unroll
        for (int j = 0; j < 3; ++j) {   // write staged chunk
            int u = j * 512 + t;
            int m = u / 24, d8 = (u % 24) * 8;
            *reinterpret_cast<uint4*>(LB + OFF_CT + (((m * 192 + d8) * 2) ^ ((m & 7) << 4))) = stT[j];
            int d = u >> 3, m8 = (u & 7) * 8;
            *reinterpret_cast<uint4*>(LB + OFF_CM + (((d * 64 + m8) * 2) ^ ((d & 7) << 4))) = stM[j];
        }
        __syncthreads();
        if (mc < 15) {                  // prefetch next chunk
            int m0 = (mc + 1) << 6;
            #pragma unroll
            for (int j = 0; j < 3; ++j) {
                int u = j * 512 + t;
                int m = u / 24, d8 = (u % 24) * 8;
                stT[j] = *reinterpret_cast<const uint4*>(x2cT + cbo + (size_t)(m0 + m) * 192 + d8);
                int d = u >> 3, m8 = (u & 7) * 8;
                stM[j] = *reinterpret_cast<const uint4*>(x2cM + cbo + (size_t)d * MM + m0 + m8);
            }
        }
        // G1: gate logits 32 rows x 32 cols per wave
        f32x4 ga[2][2];
        #pragma unroll
        for (int rt = 0; rt < 2; ++rt)
            #pragma unroll
            for (int nt = 0; nt < 2; ++nt) ga[rt][nt] = (f32x4){0.f, 0.f, 0.f, 0.f};
        #pragma unroll
        for (int nt = 0; nt < 2; ++nt) {
            int mcol = cs * 32 + nt * 16 + l15;
            #pragma unroll
            for (int k = 0; k < 6; ++k) {
                short8 bv = *reinterpret_cast<const short8*>(
                    LB + OFF_CT + (((mcol * 192 + k * 32 + l4 * 8) * 2) ^ (l7 << 4)));
                ga[0][nt] = mfma16(ax1[0][k], bv, ga[0][nt]);
                ga[1][nt] = mfma16(ax1[1][k], bv, ga[1][nt]);
            }
        }
        // sigmoid -> gate LDS (bf16, per row-group [32][88])
        #pragma unroll
        for (int rt = 0; rt < 2; ++rt)
            #pragma unroll
            for (int nt = 0; nt < 2; ++nt) {
                int colg = cs * 32 + nt * 16 + l15;
                #pragma unroll
                for (int i = 0; i < 4; ++i) {
                    float g = __fdividef(1.f, 1.f + __expf(-ga[rt][nt][i]));
                    int rowg = rt * 16 + l4 * 4 + i;
                    *reinterpret_cast<unsigned short*>(LB + OFF_GT + rg * 5632 + (rowg * 88 + colg) * 2) = bf16r(g);
                }
            }
        __syncthreads();
        // G2: sp += gate @ x2c^T  (32 rows x 96 d-cols per wave)
        short8 ag[2][2];
        #pragma unroll
        for (int rt = 0; rt < 2; ++rt)
            #pragma unroll
            for (int k2 = 0; k2 < 2; ++k2)
                ag[rt][k2] = *reinterpret_cast<const short8*>(
                    LB + OFF_GT + rg * 5632 + ((rt * 16 + l15) * 88 + k2 * 32 + l4 * 8) * 2);
        #pragma unroll
        for (int nt = 0; nt < 6; ++nt) {
            int d = cs * 96 + nt * 16 + l15;
            #pragma unroll
            for (int k2 = 0; k2 < 2; ++k2) {
                short8 bv = *reinterpret_cast<const short8*>(
                    LB + OFF_CM + (((d * 64 + k2 * 32 + l4 * 8) * 2) ^ (l7 << 4)));
                spa[0][nt] = mfma16(ag[0][k2], bv, spa[0][nt]);
                spa[1][nt] = mfma16(ag[1][k2], bv, spa[1][nt]);
            }
        }
    }

    __syncthreads();
    // write sp -> catA (bf16)
    #pragma unroll
    for (int rt = 0; rt < 2; ++rt)
        #pragma unroll
        for (int nt = 0; nt < 6; ++nt) {
            int d = cs * 96 + nt * 16 + l15;
            #pragma unroll
            for (int i = 0; i < 4; ++i) {
                int row = rg * 32 + rt * 16 + l4 * 4 + i;
                *reinterpret_cast<unsigned short*>(LB + OFF_CA + (row * 200 + d) * 2) = bf16r(spa[rt][nt][i]);
            }
        }

    // ---- Phase B: ch = x2 @ att (A from global x, B from global attT) ----
    short8 ax2[2][6];
    #pragma unroll
    for (int rt = 0; rt < 2; ++rt) {
        int row = rg * 32 + rt * 16 + l15;
        const float* src = &x[xrow0 + (size_t)row * CC + DD + l4 * 8];
        #pragma unroll
        for (int k = 0; k < 6; ++k) {
            float4 v0 = ld4(src + k * 32), v1 = ld4(src + k * 32 + 4);
            ax2[rt][k] = as_s8(make_uint4(pk2(v0.x, v0.y), pk2(v0.z, v0.w), pk2(v1.x, v1.y), pk2(v1.z, v1.w)));
        }
    }
    f32x4 cha[2][6];
    #pragma unroll
    for (int rt = 0; rt < 2; ++rt)
        #pragma unroll
        for (int nt = 0; nt < 6; ++nt) cha[rt][nt] = (f32x4){0.f, 0.f, 0.f, 0.f};
    const unsigned short* atb = attT + (size_t)b * 36864;
    #pragma unroll
    for (int nt = 0; nt < 6; ++nt) {
        int e = cs * 96 + nt * 16 + l15;
        #pragma unroll
        for (int k = 0; k < 6; ++k) {
            short8 bv = *reinterpret_cast<const short8*>(atb + (size_t)e * 192 + k * 32 + l4 * 8);
            cha[0][nt] = mfma16(ax2[0][k], bv, cha[0][nt]);
            cha[1][nt] = mfma16(ax2[1][k], bv, cha[1][nt]);
        }
    }
    // write ch -> catB (bf16)
    #pragma unroll
    for (int rt = 0; rt < 2; ++rt)
        #pragma unroll
        for (int nt = 0; nt < 6; ++nt) {
            int e = cs * 96 + nt * 16 + l15;
            #pragma unroll
            for (int i = 0; i < 4; ++i) {
                int row = rg * 32 + rt * 16 + l4 * 4 + i;
                *reinterpret_cast<unsigned short*>(LB + OFF_CB + (row * 200 + e) * 2) = bf16r(cha[rt][nt][i]);
            }
        }
    __syncthreads();

    // ---- LayerNorm: 4 threads per row, shfl stats, normalize in place ----
    {
        const int rowL = t >> 2, q = t & 3;
        const int offq = (q < 2) ? OFF_CA : OFF_CB;
        const char* lbase = LB + offq + (rowL * 200 + (q & 1) * 96) * 2;
        float s = 0.f, ss = 0.f;
        #pragma unroll
        for (int u = 0; u < 12; ++u) {
            uint4 pv = *reinterpret_cast<const uint4*>(lbase + u * 16);
            const unsigned int* pu = &pv.x;
            #pragma unroll
            for (int h = 0; h < 4; ++h) {
                float f0 = __uint_as_float(pu[h] << 16);
                float f1 = __uint_as_float(pu[h] & 0xFFFF0000u);
                s += f0 + f1; ss += f0 * f0 + f1 * f1;
            }
        }
        s += __shfl_xor(s, 1, 4);  s += __shfl_xor(s, 2, 4);
        ss += __shfl_xor(ss, 1, 4); ss += __shfl_xor(ss, 2, 4);
        float mu = s * (1.f / 384.f);
        float var = ss * (1.f / 384.f) - mu * mu;
        float rs = rsqrtf(var + 1e-5f);
        const int c0 = q * 96;
        #pragma unroll
        for (int u = 0; u < 12; ++u) {
            uint4 pv = *reinterpret_cast<const uint4*>(lbase + u * 16);
            const unsigned int* pu = &pv.x;
            float4 w0 = ld4(&lnw[c0 + u * 8]), w1 = ld4(&lnw[c0 + u * 8 + 4]);
            float4 b0 = ld4(&lnb[c0 + u * 8]), b1 = ld4(&lnb[c0 + u * 8 + 4]);
            float f[8];
            #pragma unroll
            for (int h = 0; h < 4; ++h) {
                f[2 * h]     = __uint_as_float(pu[h] << 16);
                f[2 * h + 1] = __uint_as_float(pu[h] & 0xFFFF0000u);
            }
            f[0] = (f[0] - mu) * rs * w0.x + b0.x; f[1] = (f[1] - mu) * rs * w0.y + b0.y;
            f[2] = (f[2] - mu) * rs * w0.z + b0.z; f[3] = (f[3] - mu) * rs * w0.w + b0.w;
            f[4] = (f[4] - mu) * rs * w1.x + b1.x; f[5] = (f[5] - mu) * rs * w1.y + b1.y;
            f[6] = (f[6] - mu) * rs * w1.z + b1.z; f[7] = (f[7] - mu) * rs * w1.w + b1.w;
            uint4 ov = make_uint4(pk2(f[0], f[1]), pk2(f[2], f[3]), pk2(f[4], f[5]), pk2(f[6], f[7]));
            *reinterpret_cast<uint4*>(const_cast<char*>(lbase) + u * 16) = ov;
        }
    }

    // ---- Phase C: proj (K=384 in 12 k-tiles, pw staged in LDS) ----
    f32x4 pacc[2][12];
    #pragma unroll
    for (int rt = 0; rt < 2; ++rt)
        #pragma unroll
        for (int nt = 0; nt < 12; ++nt) pacc[rt][nt] = (f32x4){0.f, 0.f, 0.f, 0.f};
    for (int kt = 0; kt < 12; ++kt) {
        __syncthreads();
        #pragma unroll
        for (int j = 0; j < 3; ++j) {
            int u = j * 512 + t;
            int o = u >> 2, c8 = (u & 3) * 8;
            uint4 pv = *reinterpret_cast<const uint4*>(pwb + (size_t)o * CC + kt * 32 + c8);
            *reinterpret_cast<uint4*>(LB + OFF_PW + (((o * 32 + c8) * 2) ^ ((o & 7) << 4))) = pv;
        }
        __syncthreads();
        short8 av[2];
        const int offc = (kt < 6) ? OFF_CA : OFF_CB;
        const int cl = (kt % 6) * 32 + l4 * 8;
        #pragma unroll
        for (int rt = 0; rt < 2; ++rt) {
            int row = rg * 32 + rt * 16 + l15;
            av[rt] = *reinterpret_cast<const short8*>(LB + offc + (row * 200 + cl) * 2);
        }
        #pragma unroll
        for (int nt = 0; nt < 12; ++nt) {
            int o = cs * 192 + nt * 16 + l15;
            short8 bv = *reinterpret_cast<const short8*>(
                LB + OFF_PW + (((o * 32 + l4 * 8) * 2) ^ (l7 << 4)));
            pacc[0][nt] = mfma16(av[0], bv, pacc[0][nt]);
            pacc[1][nt] = mfma16(av[1], bv, pacc[1][nt]);
        }
    }

    // ---- epilogue: bias + transposed store ----
    #pragma unroll
    for (int nt = 0; nt < 12; ++nt) {
        int o = cs * 192 + nt * 16 + l15;
        float bias = pb[o];
        #pragma unroll
        for (int rt = 0; rt < 2; ++rt) {
            float4 ov;
            ov.x = pacc[rt][nt][0] + bias;
            ov.y = pacc[rt][nt][1] + bias;
            ov.z = pacc[rt][nt][2] + bias;
            ov.w = pacc[rt][nt][3] + bias;
            size_t off = (size_t)(b * CC + o) * NN + n0 + rg * 32 + rt * 16 + l4 * 4;
            *reinterpret_cast<float4*>(&out[off]) = ov;
        }
    }
}

extern "C" void kernel_launch(void* const* d_in, const int* in_sizes, int n_in,
                              void* d_out, int out_size, void* d_ws, size_t ws_size,
                              hipStream_t stream)
{
    (void)in_sizes; (void)n_in; (void)out_size; (void)ws_size;
    const float* x   = (const float*)d_in[0];
    const float* cw  = (const float*)d_in[1];
    const float* cb  = (const float*)d_in[2];
    const float* lnw = (const float*)d_in[3];
    const float* lnb = (const float*)d_in[4];
    const float* pwm = (const float*)d_in[5];
    const float* pbv = (const float*)d_in[6];
    float* out = (float*)d_out;
    char* w0 = (char*)d_ws;

    unsigned short* x2cT = (unsigned short*)(w0);
    unsigned short* x2cM = (unsigned short*)(w0 + 1572864);
    unsigned short* attT = (unsigned short*)(w0 + 3145728);
    unsigned short* pwb  = (unsigned short*)(w0 + 3440640);
    float* Sp = (float*)(w0 + 3735552);
    float* Sf = (float*)(w0 + 8454144);

    hipLaunchKernelGGL(k_prep,    dim3(144),      dim3(256), 0, stream, pwm, pwb);
    hipLaunchKernelGGL(k_conv,    dim3(BB * 64),  dim3(256), 0, stream, x, cw, cb, x2cT, x2cM);
    hipLaunchKernelGGL(k_spart,   dim3(BB * 48),  dim3(256), 0, stream, x, Sp);
    hipLaunchKernelGGL(k_sreduce, dim3(576),      dim3(256), 0, stream, Sp, Sf);
    hipLaunchKernelGGL(k_softmax, dim3(BB * 192), dim3(64),  0, stream, Sf, attT);
    hipLaunchKernelGGL(k_fused,   dim3(BB * 128), dim3(512), 0, stream,
                       x, x2cT, x2cM, attT, lnw, lnb, pwb, pbv, out);
}

// Round 3
// 384.323 us; speedup vs baseline: 6.1150x; 1.6716x over previous
//
#include <hip/hip_runtime.h>

#define BB 4
#define NN 16384
#define CC 384
#define DD 192
#define MM 1024

typedef __attribute__((ext_vector_type(8))) short short8;
typedef __attribute__((ext_vector_type(4))) float f32x4;

__device__ __forceinline__ float4 ld4(const float* p) { return *reinterpret_cast<const float4*>(p); }

__device__ __forceinline__ unsigned short bf16r(float f) {
    unsigned int u = __float_as_uint(f);
    return (unsigned short)((u + 0x7FFFu + ((u >> 16) & 1u)) >> 16);
}
__device__ __forceinline__ unsigned int pk2(float a, float b) {
    return (unsigned int)bf16r(a) | ((unsigned int)bf16r(b) << 16);
}
__device__ __forceinline__ short8 as_s8(uint4 v) {
    union { uint4 u; short8 s; } x; x.u = v; return x.s;
}
__device__ __forceinline__ f32x4 mfma16(short8 a, short8 b, f32x4 c) {
    return __builtin_amdgcn_mfma_f32_16x16x32_bf16(a, b, c, 0, 0, 0);
}

// ---------------- K0a: proj_w fp32 -> bf16 ----------------
__global__ __launch_bounds__(256) void k_prep(const float* __restrict__ pw, unsigned short* __restrict__ pwb)
{
    int i = blockIdx.x * 256 + threadIdx.x;
    float4 v = ld4(&pw[i * 4]);
    uint2 o; o.x = pk2(v.x, v.y); o.y = pk2(v.z, v.w);
    reinterpret_cast<uint2*>(pwb)[i] = o;
}

// ---------------- K0b: conv_w -> cwb[k8][o][8] bf16, k = px*192 + i ----------------
__global__ __launch_bounds__(256) void k_prepw(const float* __restrict__ cw, unsigned short* __restrict__ cwb)
{
    int idx = blockIdx.x * 256 + threadIdx.x;   // 73728 = 384 k8 * 192 o
    int k8 = idx / 192, o = idx % 192;
    int px = k8 / 24;                            // k = k8*8: px = k/192
    int i0 = (k8 % 24) * 8;
    float f[8];
    #pragma unroll
    for (int e = 0; e < 8; ++e) f[e] = cw[(size_t)(o * 192 + i0 + e) * 16 + px];
    uint4 v = make_uint4(pk2(f[0], f[1]), pk2(f[2], f[3]), pk2(f[4], f[5]), pk2(f[6], f[7]));
    reinterpret_cast<uint4*>(cwb)[idx] = v;
}

// ---------------- K1: conv via MFMA, px-split x2 -> partials Cp2[s][P][o] ----------------
__global__ __launch_bounds__(256) void k_conv(const float* __restrict__ x,
                                              const unsigned short* __restrict__ cwb,
                                              float* __restrict__ Cp2)
{
    const int bid = blockIdx.x;
    const int s = bid >> 8, pt = bid & 255;
    const int b = pt >> 6;
    const int m0 = (pt & 63) * 16;
    const int P0 = pt * 16;
    const int t = threadIdx.x;
    const int l = t & 63, w = t >> 6;
    const int l15 = l & 15, l4 = l >> 4;
    const int o0 = w * 48;

    const int m = m0 + l15;
    const int ph = m >> 5, pw_ = m & 31;
    const float* xp = x + ((size_t)(b * NN) + ph * 512 + pw_ * 4) * CC + DD;

    f32x4 acc[3];
    #pragma unroll
    for (int ft = 0; ft < 3; ++ft) acc[ft] = (f32x4){0.f, 0.f, 0.f, 0.f};

    for (int kt = 0; kt < 48; ++kt) {
        const int px = s * 8 + kt / 6;
        const int i0 = (kt % 6) * 32;
        const int kh = px >> 2, kw = px & 3;
        const float* src = xp + (size_t)(kh * 128 + kw) * CC + i0 + l4 * 8;
        float4 v0 = ld4(src), v1 = ld4(src + 4);
        short8 av = as_s8(make_uint4(pk2(v0.x, v0.y), pk2(v0.z, v0.w), pk2(v1.x, v1.y), pk2(v1.z, v1.w)));
        const int k8g = px * 24 + (kt % 6) * 4 + l4;
        #pragma unroll
        for (int ft = 0; ft < 3; ++ft) {
            int o = o0 + ft * 16 + l15;
            short8 bv = as_s8(*reinterpret_cast<const uint4*>(cwb + (size_t)(k8g * 192 + o) * 8));
            acc[ft] = mfma16(av, bv, acc[ft]);
        }
    }
    #pragma unroll
    for (int ft = 0; ft < 3; ++ft)
        #pragma unroll
        for (int i = 0; i < 4; ++i)
            Cp2[(size_t)(s * 4096 + P0 + l4 * 4 + i) * 192 + o0 + ft * 16 + l15] = acc[ft][i];
}

// ---------------- K1b: reduce px-splits + bias -> x2cT (bf16 [m][d]) and x2cM (bf16 [d][m]) ----------------
__global__ __launch_bounds__(256) void k_convred(const float* __restrict__ Cp2,
                                                 const float* __restrict__ cb,
                                                 unsigned short* __restrict__ x2cT,
                                                 unsigned short* __restrict__ x2cM)
{
    __shared__ unsigned short T[64 * 194];
    const int bid = blockIdx.x;                 // 64 = 4 b x 16 mc
    const int b = bid >> 4, mc = bid & 15;
    const int P0 = b * 1024 + mc * 64;
    const int t = threadIdx.x;
    #pragma unroll
    for (int j = 0; j < 12; ++j) {
        int idx = j * 256 + t;                  // 3072 float4 = 64 rows x 48
        int row = idx / 48, c4 = idx % 48;
        float4 v0 = ld4(&Cp2[(size_t)(P0 + row) * 192 + c4 * 4]);
        float4 v1 = ld4(&Cp2[(size_t)(4096 + P0 + row) * 192 + c4 * 4]);
        float4 bb = ld4(&cb[c4 * 4]);
        float r0 = v0.x + v1.x + bb.x, r1 = v0.y + v1.y + bb.y;
        float r2 = v0.z + v1.z + bb.z, r3 = v0.w + v1.w + bb.w;
        unsigned short h0 = bf16r(r0), h1 = bf16r(r1), h2 = bf16r(r2), h3 = bf16r(r3);
        uint2 ov; ov.x = (unsigned int)h0 | ((unsigned int)h1 << 16);
        ov.y = (unsigned int)h2 | ((unsigned int)h3 << 16);
        *reinterpret_cast<uint2*>(x2cT + (size_t)(P0 + row) * 192 + c4 * 4) = ov;
        T[row * 194 + c4 * 4 + 0] = h0; T[row * 194 + c4 * 4 + 1] = h1;
        T[row * 194 + c4 * 4 + 2] = h2; T[row * 194 + c4 * 4 + 3] = h3;
    }
    __syncthreads();
    #pragma unroll
    for (int j = 0; j < 6; ++j) {
        int u = j * 256 + t;                    // 1536 = 192 o x 8 m-octets
        int o = u >> 3, m8 = (u & 7) * 8;
        unsigned int pk[4];
        #pragma unroll
        for (int q = 0; q < 4; ++q) {
            unsigned short a = T[(m8 + q * 2) * 194 + o];
            unsigned short c = T[(m8 + q * 2 + 1) * 194 + o];
            pk[q] = (unsigned int)a | ((unsigned int)c << 16);
        }
        *reinterpret_cast<uint4*>(x2cM + ((size_t)(b * DD + o) * MM) + mc * 64 + m8) =
            make_uint4(pk[0], pk[1], pk[2], pk[3]);
    }
}

// ---------------- K2: S partials via bf16 hi/lo MFMA (3-product compensation) ----------------
__global__ __launch_bounds__(512) void k_S(const float* __restrict__ x, float* __restrict__ Sp)
{
    __shared__ char LS[384 * 128];              // row c: 32 hi bf16 | 32 lo bf16 (128B), XOR swizzled
    const int bid = blockIdx.x;                 // 128 = 4 b x 32 ks
    const int b = bid >> 5, ks = bid & 31;
    const int n0 = ks * 512;
    const int t = threadIdx.x;
    const int l = t & 63, w = t >> 6;
    const int rg = w >> 2, cs = w & 3;
    const int l15 = l & 15, l4 = l >> 4, key = (l15 & 7) << 4;

    const int c0 = (t & 127) * 3;
    const int krow = t >> 7;                    // 0..3

    f32x4 acc[6][3];
    #pragma unroll
    for (int dt = 0; dt < 6; ++dt)
        #pragma unroll
        for (int et = 0; et < 3; ++et) acc[dt][et] = (f32x4){0.f, 0.f, 0.f, 0.f};

    for (int kt = 0; kt < 16; ++kt) {
        __syncthreads();
        // stage 32 rows x 384 c transposed, hi/lo split
        #pragma unroll
        for (int i = 0; i < 8; ++i) {
            int k = i * 4 + krow;
            const float* src = &x[(size_t)(b * NN + n0 + kt * 32 + k) * CC + c0];
            #pragma unroll
            for (int j = 0; j < 3; ++j) {
                int c = c0 + j;
                float v = src[j];
                unsigned short hi = bf16r(v);
                float hif = __uint_as_float(((unsigned int)hi) << 16);
                unsigned short lo = bf16r(v - hif);
                int base = c * 128;
                int ck = (c & 7) << 4;
                *reinterpret_cast<unsigned short*>(LS + base + ((k * 2) ^ ck)) = hi;
                *reinterpret_cast<unsigned short*>(LS + base + ((64 + k * 2) ^ ck)) = lo;
            }
        }
        __syncthreads();
        short8 bf[3][2];
        #pragma unroll
        for (int et = 0; et < 3; ++et) {
            int c = 192 + cs * 48 + et * 16 + l15;
            #pragma unroll
            for (int hl = 0; hl < 2; ++hl)
                bf[et][hl] = *reinterpret_cast<const short8*>(LS + c * 128 + ((hl * 64 + l4 * 16) ^ key));
        }
        #pragma unroll
        for (int dt = 0; dt < 6; ++dt) {
            int c = rg * 96 + dt * 16 + l15;
            short8 ah = *reinterpret_cast<const short8*>(LS + c * 128 + ((l4 * 16) ^ key));
            short8 al = *reinterpret_cast<const short8*>(LS + c * 128 + ((64 + l4 * 16) ^ key));
            #pragma unroll
            for (int et = 0; et < 3; ++et) {
                acc[dt][et] = mfma16(ah, bf[et][0], acc[dt][et]);
                acc[dt][et] = mfma16(ah, bf[et][1], acc[dt][et]);
                acc[dt][et] = mfma16(al, bf[et][0], acc[dt][et]);
            }
        }
    }
    float* dst = Sp + (size_t)(ks * BB + b) * 36864;
    #pragma unroll
    for (int dt = 0; dt < 6; ++dt)
        #pragma unroll
        for (int et = 0; et < 3; ++et) {
            int e = cs * 48 + et * 16 + l15;
            #pragma unroll
            for (int i = 0; i < 4; ++i) {
                int d = rg * 96 + dt * 16 + l4 * 4 + i;
                dst[d * 192 + e] = acc[dt][et][i];
            }
        }
}

// ---------------- K2b: reduce 32 partials -> S ----------------
__global__ __launch_bounds__(256) void k_sreduce(const float* __restrict__ Sp, float* __restrict__ S)
{
    int idx = blockIdx.x * 256 + threadIdx.x;
    int b = idx / 36864, de = idx % 36864;
    float s = 0.f;
    #pragma unroll
    for (int p = 0; p < 32; ++p) s += Sp[(size_t)(p * BB + b) * 36864 + de];
    S[(size_t)b * 36864 + de] = s;
}

// ---------------- K2c: softmax over d -> attT[b][e][d] bf16 ----------------
__global__ __launch_bounds__(64) void k_softmax(const float* __restrict__ S, unsigned short* __restrict__ attT)
{
    const int bid = blockIdx.x;
    const int b = bid / 192, e = bid % 192;
    const int l = threadIdx.x;
    const float* Sb = S + (size_t)b * 36864 + e;
    float v0 = Sb[(size_t)(l * 3 + 0) * 192];
    float v1 = Sb[(size_t)(l * 3 + 1) * 192];
    float v2 = Sb[(size_t)(l * 3 + 2) * 192];
    float m = fmaxf(fmaxf(v0, v1), v2);
    #pragma unroll
    for (int s = 1; s < 64; s <<= 1) m = fmaxf(m, __shfl_xor(m, s, 64));
    v0 = __expf(v0 - m); v1 = __expf(v1 - m); v2 = __expf(v2 - m);
    float sum = v0 + v1 + v2;
    #pragma unroll
    for (int s = 1; s < 64; s <<= 1) sum += __shfl_xor(sum, s, 64);
    float inv = __fdividef(1.f, sum);
    unsigned short* dst = attT + (size_t)b * 36864 + (size_t)e * 192 + l * 3;
    dst[0] = bf16r(v0 * inv); dst[1] = bf16r(v1 * inv); dst[2] = bf16r(v2 * inv);
}

// ---------------- K4: fused MFMA kernel, 1024 thr, 16 waves, 128 rows ----------------
#define OFF_CT(p) ((p) * 49152)
#define OFF_CM(p) ((p) * 49152 + 24576)
#define OFF_GT 98304
#define OFF_PW 100352

__global__ __launch_bounds__(1024) void k_fused(
    const float* __restrict__ x, const unsigned short* __restrict__ x2cT,
    const unsigned short* __restrict__ x2cM, const unsigned short* __restrict__ attT,
    const float* __restrict__ lnw, const float* __restrict__ lnb,
    const unsigned short* __restrict__ pwb, const float* __restrict__ pb,
    float* __restrict__ out)
{
    __shared__ alignas(16) char LB[124928];
    const int t = threadIdx.x;
    const int l = t & 63, w = t >> 6;
    const int rg = w >> 2, cs = w & 3;
    const int b = blockIdx.x >> 7;
    const int n0 = (blockIdx.x & 127) << 7;
    const int l15 = l & 15, l4 = l >> 4, key = (l15 & 7) << 4;
    const size_t xrow0 = (size_t)(b * NN + n0) * CC;
    const size_t cbo = (size_t)b * 196608;

    uint4 st[3];
    // prologue: load + write chunk 0
    #pragma unroll
    for (int j = 0; j < 3; ++j) {
        int u = j * 1024 + t;
        if (u < 1536) {
            int m = u / 24, d8 = (u % 24) * 8;
            st[j] = *reinterpret_cast<const uint4*>(x2cT + cbo + (size_t)m * 192 + d8);
        } else {
            int v = u - 1536;
            int d = v >> 3, m8 = (v & 7) * 8;
            st[j] = *reinterpret_cast<const uint4*>(x2cM + cbo + (size_t)d * MM + m8);
        }
    }
    #pragma unroll
    for (int j = 0; j < 3; ++j) {
        int u = j * 1024 + t;
        if (u < 1536) {
            int m = u / 24, d8 = (u % 24) * 8;
            *reinterpret_cast<uint4*>(LB + OFF_CT(0) + (((m * 192 + d8) * 2) ^ ((m & 7) << 4))) = st[j];
        } else {
            int v = u - 1536;
            int d = v >> 3, m8 = (v & 7) * 8;
            *reinterpret_cast<uint4*>(LB + OFF_CM(0) + (((d * 64 + m8) * 2) ^ ((d & 7) << 4))) = st[j];
        }
    }
    // x1 A-fragments from global (bf16-pack)
    short8 ax1[2][6];
    #pragma unroll
    for (int rt = 0; rt < 2; ++rt) {
        int row = rg * 32 + rt * 16 + l15;
        const float* src = &x[xrow0 + (size_t)row * CC + l4 * 8];
        #pragma unroll
        for (int k = 0; k < 6; ++k) {
            float4 v0 = ld4(src + k * 32), v1 = ld4(src + k * 32 + 4);
            ax1[rt][k] = as_s8(make_uint4(pk2(v0.x, v0.y), pk2(v0.z, v0.w), pk2(v1.x, v1.y), pk2(v1.z, v1.w)));
        }
    }
    __syncthreads();

    f32x4 spa[2][3];
    #pragma unroll
    for (int rt = 0; rt < 2; ++rt)
        #pragma unroll
        for (int nt = 0; nt < 3; ++nt) spa[rt][nt] = (f32x4){0.f, 0.f, 0.f, 0.f};

    // ---- Phase A ----
    for (int mc = 0; mc < 16; ++mc) {
        const int p = mc & 1;
        if (mc < 15) {
            const int m0 = (mc + 1) << 6;
            #pragma unroll
            for (int j = 0; j < 3; ++j) {
                int u = j * 1024 + t;
                if (u < 1536) {
                    int m = u / 24, d8 = (u % 24) * 8;
                    st[j] = *reinterpret_cast<const uint4*>(x2cT + cbo + (size_t)(m0 + m) * 192 + d8);
                } else {
                    int v = u - 1536;
                    int d = v >> 3, m8 = (v & 7) * 8;
                    st[j] = *reinterpret_cast<const uint4*>(x2cM + cbo + (size_t)d * MM + m0 + m8);
                }
            }
        }
        // G1: gate logits, 32 rows x 16 m per wave
        f32x4 ga[2];
        ga[0] = (f32x4){0.f, 0.f, 0.f, 0.f};
        ga[1] = (f32x4){0.f, 0.f, 0.f, 0.f};
        {
            const int mcol = cs * 16 + l15;
            const char* base = LB + OFF_CT(p) + mcol * 384;
            #pragma unroll
            for (int k = 0; k < 6; ++k) {
                short8 bv = *reinterpret_cast<const short8*>(base + ((k * 64 + l4 * 16) ^ key));
                ga[0] = mfma16(ax1[0][k], bv, ga[0]);
                ga[1] = mfma16(ax1[1][k], bv, ga[1]);
            }
        }
        // sigmoid -> GT[rg][row][m]
        #pragma unroll
        for (int rt = 0; rt < 2; ++rt)
            #pragma unroll
            for (int i = 0; i < 4; ++i) {
                float g = __fdividef(1.f, 1.f + __expf(-ga[rt][i]));
                *reinterpret_cast<unsigned short*>(LB + OFF_GT + rg * 5632 +
                    ((rt * 16 + l4 * 4 + i) * 88 + cs * 16 + l15) * 2) = bf16r(g);
            }
        __syncthreads();
        // G2: sp += gate @ x2c^T, 32 rows x 48 d per wave
        short8 ag[2][2];
        #pragma unroll
        for (int rt = 0; rt < 2; ++rt)
            #pragma unroll
            for (int k2 = 0; k2 < 2; ++k2)
                ag[rt][k2] = *reinterpret_cast<const short8*>(
                    LB + OFF_GT + rg * 5632 + ((rt * 16 + l15) * 88 + k2 * 32 + l4 * 8) * 2);
        #pragma unroll
        for (int nt = 0; nt < 3; ++nt) {
            const int d = cs * 48 + nt * 16 + l15;
            const char* base = LB + OFF_CM(p) + d * 128;
            #pragma unroll
            for (int k2 = 0; k2 < 2; ++k2) {
                short8 bv = *reinterpret_cast<const short8*>(base + ((k2 * 64 + l4 * 16) ^ key));
                spa[0][nt] = mfma16(ag[0][k2], bv, spa[0][nt]);
                spa[1][nt] = mfma16(ag[1][k2], bv, spa[1][nt]);
            }
        }
        if (mc < 15) {
            #pragma unroll
            for (int j = 0; j < 3; ++j) {
                int u = j * 1024 + t;
                if (u < 1536) {
                    int m = u / 24, d8 = (u % 24) * 8;
                    *reinterpret_cast<uint4*>(LB + OFF_CT(p ^ 1) + (((m * 192 + d8) * 2) ^ ((m & 7) << 4))) = st[j];
                } else {
                    int v = u - 1536;
                    int d = v >> 3, m8 = (v & 7) * 8;
                    *reinterpret_cast<uint4*>(LB + OFF_CM(p ^ 1) + (((d * 64 + m8) * 2) ^ ((d & 7) << 4))) = st[j];
                }
            }
        }
        __syncthreads();
    }

    // write sp -> cat (bf16, pitch 392 ushorts)
    #pragma unroll
    for (int rt = 0; rt < 2; ++rt)
        #pragma unroll
        for (int nt = 0; nt < 3; ++nt) {
            int d = cs * 48 + nt * 16 + l15;
            #pragma unroll
            for (int i = 0; i < 4; ++i) {
                int row = rg * 32 + rt * 16 + l4 * 4 + i;
                *reinterpret_cast<unsigned short*>(LB + row * 784 + d * 2) = bf16r(spa[rt][nt][i]);
            }
        }

    // ---- Phase B: ch = x2 @ att ----
    short8 ax2[2][6];
    #pragma unroll
    for (int rt = 0; rt < 2; ++rt) {
        int row = rg * 32 + rt * 16 + l15;
        const float* src = &x[xrow0 + (size_t)row * CC + DD + l4 * 8];
        #pragma unroll
        for (int k = 0; k < 6; ++k) {
            float4 v0 = ld4(src + k * 32), v1 = ld4(src + k * 32 + 4);
            ax2[rt][k] = as_s8(make_uint4(pk2(v0.x, v0.y), pk2(v0.z, v0.w), pk2(v1.x, v1.y), pk2(v1.z, v1.w)));
        }
    }
    f32x4 cha[2][3];
    #pragma unroll
    for (int rt = 0; rt < 2; ++rt)
        #pragma unroll
        for (int nt = 0; nt < 3; ++nt) cha[rt][nt] = (f32x4){0.f, 0.f, 0.f, 0.f};
    const unsigned short* atb = attT + (size_t)b * 36864;
    #pragma unroll
    for (int nt = 0; nt < 3; ++nt) {
        int e = cs * 48 + nt * 16 + l15;
        #pragma unroll
        for (int k = 0; k < 6; ++k) {
            short8 bv = *reinterpret_cast<const short8*>(atb + (size_t)e * 192 + k * 32 + l4 * 8);
            cha[0][nt] = mfma16(ax2[0][k], bv, cha[0][nt]);
            cha[1][nt] = mfma16(ax2[1][k], bv, cha[1][nt]);
        }
    }
    #pragma unroll
    for (int rt = 0; rt < 2; ++rt)
        #pragma unroll
        for (int nt = 0; nt < 3; ++nt) {
            int e = cs * 48 + nt * 16 + l15;
            #pragma unroll
            for (int i = 0; i < 4; ++i) {
                int row = rg * 32 + rt * 16 + l4 * 4 + i;
                *reinterpret_cast<unsigned short*>(LB + row * 784 + (DD + e) * 2) = bf16r(cha[rt][nt][i]);
            }
        }
    __syncthreads();

    // ---- LayerNorm: 8 threads/row ----
    {
        const int rowL = t >> 3, q = t & 7;
        char* lbase = LB + rowL * 784 + q * 96;
        float s = 0.f, ss = 0.f;
        #pragma unroll
        for (int u = 0; u < 6; ++u) {
            uint4 pv = *reinterpret_cast<const uint4*>(lbase + u * 16);
            const unsigned int* pu = &pv.x;
            #pragma unroll
            for (int h = 0; h < 4; ++h) {
                float f0 = __uint_as_float(pu[h] << 16);
                float f1 = __uint_as_float(pu[h] & 0xFFFF0000u);
                s += f0 + f1; ss += f0 * f0 + f1 * f1;
            }
        }
        s += __shfl_xor(s, 1, 8);  s += __shfl_xor(s, 2, 8);  s += __shfl_xor(s, 4, 8);
        ss += __shfl_xor(ss, 1, 8); ss += __shfl_xor(ss, 2, 8); ss += __shfl_xor(ss, 4, 8);
        float mu = s * (1.f / 384.f);
        float var = ss * (1.f / 384.f) - mu * mu;
        float rs = rsqrtf(var + 1e-5f);
        const int c0 = q * 48;
        #pragma unroll
        for (int u = 0; u < 6; ++u) {
            uint4 pv = *reinterpret_cast<const uint4*>(lbase + u * 16);
            const unsigned int* pu = &pv.x;
            float4 w0 = ld4(&lnw[c0 + u * 8]), w1 = ld4(&lnw[c0 + u * 8 + 4]);
            float4 b0 = ld4(&lnb[c0 + u * 8]), b1 = ld4(&lnb[c0 + u * 8 + 4]);
            float f[8];
            #pragma unroll
            for (int h = 0; h < 4; ++h) {
                f[2 * h]     = __uint_as_float(pu[h] << 16);
                f[2 * h + 1] = __uint_as_float(pu[h] & 0xFFFF0000u);
            }
            f[0] = (f[0] - mu) * rs * w0.x + b0.x; f[1] = (f[1] - mu) * rs * w0.y + b0.y;
            f[2] = (f[2] - mu) * rs * w0.z + b0.z; f[3] = (f[3] - mu) * rs * w0.w + b0.w;
            f[4] = (f[4] - mu) * rs * w1.x + b1.x; f[5] = (f[5] - mu) * rs * w1.y + b1.y;
            f[6] = (f[6] - mu) * rs * w1.z + b1.z; f[7] = (f[7] - mu) * rs * w1.w + b1.w;
            *reinterpret_cast<uint4*>(lbase + u * 16) =
                make_uint4(pk2(f[0], f[1]), pk2(f[2], f[3]), pk2(f[4], f[5]), pk2(f[6], f[7]));
        }
    }
    __syncthreads();

    // ---- Phase C: proj ----
    f32x4 pacc[2][6];
    #pragma unroll
    for (int rt = 0; rt < 2; ++rt)
        #pragma unroll
        for (int nt = 0; nt < 6; ++nt) pacc[rt][nt] = (f32x4){0.f, 0.f, 0.f, 0.f};
    for (int kt = 0; kt < 12; ++kt) {
        #pragma unroll
        for (int j = 0; j < 2; ++j) {
            int u = j * 1024 + t;
            if (u < 1536) {
                int o = u >> 2, c8 = (u & 3) * 8;
                uint4 pv = *reinterpret_cast<const uint4*>(pwb + (size_t)o * CC + kt * 32 + c8);
                *reinterpret_cast<uint4*>(LB + OFF_PW + (((o * 32 + c8) * 2) ^ ((o & 7) << 4))) = pv;
            }
        }
        __syncthreads();
        short8 av[2];
        #pragma unroll
        for (int rt = 0; rt < 2; ++rt) {
            int row = rg * 32 + rt * 16 + l15;
            av[rt] = *reinterpret_cast<const short8*>(LB + row * 784 + kt * 64 + l4 * 16);
        }
        #pragma unroll
        for (int nt = 0; nt < 6; ++nt) {
            int o = cs * 96 + nt * 16 + l15;
            short8 bv = *reinterpret_cast<const short8*>(
                LB + OFF_PW + (((o * 32 + l4 * 8) * 2) ^ ((o & 7) << 4)));
            pacc[0][nt] = mfma16(av[0], bv, pacc[0][nt]);
            pacc[1][nt] = mfma16(av[1], bv, pacc[1][nt]);
        }
        __syncthreads();
    }

    // ---- epilogue ----
    #pragma unroll
    for (int nt = 0; nt < 6; ++nt) {
        int o = cs * 96 + nt * 16 + l15;
        float bias = pb[o];
        #pragma unroll
        for (int rt = 0; rt < 2; ++rt) {
            float4 ov;
            ov.x = pacc[rt][nt][0] + bias;
            ov.y = pacc[rt][nt][1] + bias;
            ov.z = pacc[rt][nt][2] + bias;
            ov.w = pacc[rt][nt][3] + bias;
            size_t off = (size_t)(b * CC + o) * NN + n0 + rg * 32 + rt * 16 + l4 * 4;
            *reinterpret_cast<float4*>(&out[off]) = ov;
        }
    }
}

extern "C" void kernel_launch(void* const* d_in, const int* in_sizes, int n_in,
                              void* d_out, int out_size, void* d_ws, size_t ws_size,
                              hipStream_t stream)
{
    (void)in_sizes; (void)n_in; (void)out_size; (void)ws_size;
    const float* x   = (const float*)d_in[0];
    const float* cw  = (const float*)d_in[1];
    const float* cb  = (const float*)d_in[2];
    const float* lnw = (const float*)d_in[3];
    const float* lnb = (const float*)d_in[4];
    const float* pwm = (const float*)d_in[5];
    const float* pbv = (const float*)d_in[6];
    float* out = (float*)d_out;
    char* w0 = (char*)d_ws;

    unsigned short* x2cT = (unsigned short*)(w0);              // 1572864 B
    unsigned short* x2cM = (unsigned short*)(w0 + 1572864);    // 1572864 B
    unsigned short* attT = (unsigned short*)(w0 + 3145728);    // 294912 B
    unsigned short* pwb  = (unsigned short*)(w0 + 3440640);    // 294912 B
    unsigned short* cwb  = (unsigned short*)(w0 + 3735552);    // 1179648 B
    float* Cp2 = (float*)(w0 + 4915200);                       // 6291456 B
    float* Sp  = (float*)(w0 + 11206656);                      // 18874368 B
    float* Sf  = (float*)(w0 + 30081024);                      // 589824 B

    hipLaunchKernelGGL(k_prep,    dim3(144),      dim3(256),  0, stream, pwm, pwb);
    hipLaunchKernelGGL(k_prepw,   dim3(288),      dim3(256),  0, stream, cw, cwb);
    hipLaunchKernelGGL(k_conv,    dim3(512),      dim3(256),  0, stream, x, cwb, Cp2);
    hipLaunchKernelGGL(k_convred, dim3(64),       dim3(256),  0, stream, Cp2, cb, x2cT, x2cM);
    hipLaunchKernelGGL(k_S,       dim3(128),      dim3(512),  0, stream, x, Sp);
    hipLaunchKernelGGL(k_sreduce, dim3(576),      dim3(256),  0, stream, Sp, Sf);
    hipLaunchKernelGGL(k_softmax, dim3(BB * 192), dim3(64),   0, stream, Sf, attT);
    hipLaunchKernelGGL(k_fused,   dim3(BB * 128), dim3(1024), 0, stream,
                       x, x2cT, x2cM, attT, lnw, lnb, pwb, pbv, out);
}